// Round 1
// baseline (348.707 us; speedup 1.0000x reference)
//
#include <hip/hip_runtime.h>

#define NPTS 50000
#define KNB 16
#define FDIM 64
#define OUTC 64
#define FAN 1024   // KNB*FDIM
#define NBL 4      // n values per block

typedef __attribute__((ext_vector_type(4))) float f32x4;
typedef __attribute__((ext_vector_type(8))) short bf16x8;

__device__ __forceinline__ unsigned short f2bf(float f) {
    union { float f; unsigned u; } a; a.f = f;
    return (unsigned short)((a.u + 0x7fffu + ((a.u >> 16) & 1u)) >> 16);
}

// one-time (per launch) conversion of W [64][1024] f32 -> bf16 in d_ws
__global__ void wconv_kernel(const float* __restrict__ W, unsigned short* __restrict__ Wb) {
    int i = blockIdx.x * 256 + threadIdx.x;
    Wb[i] = f2bf(W[i]);
}

template<int USEWB>
__global__ __launch_bounds__(256, 2)
void paiconv_kernel(const float* __restrict__ x, const float* __restrict__ v,
                    const float* __restrict__ aw, const float* __restrict__ W,
                    const unsigned short* __restrict__ Wb,
                    const float* __restrict__ bias, const int* __restrict__ nbr,
                    float* __restrict__ out)
{
    // yel rows padded to 1032 bf16 (2064 B = 16*129) -> b128-aligned, ~2-way banks
    __shared__ __align__(16) unsigned short yel[16][1032]; // 33 KB
    __shared__ float adjs[4][256];                         // 4 KB, [k][t] per wave
    __shared__ int idxs[4][4][KNB];                        // 1 KB

    const int tid  = threadIdx.x;
    const int w    = tid >> 6;   // wave id = which n of the 4
    const int lane = tid & 63;
    const int n0   = blockIdx.x * NBL;
    const int n    = n0 + w;

    // ---- phase 1: per-wave, point group (n, all 4 batches) ----
    {   // neighbor indices: lane l -> (batch pp, k)
        int pp = lane >> 4, k = lane & 15;
        idxs[w][pp][k] = nbr[(pp * NPTS + n) * KNB + k];
    }

    // adj[n][k][t] = sum_s v[n][s] * adjweight[s][k][t]; 4 entries per lane
    f32x4 v0 = *(const f32x4*)&v[n * 8];
    f32x4 v1 = *(const f32x4*)&v[n * 8 + 4];
    #pragma unroll
    for (int j = 0; j < 4; ++j) {
        int kt = lane + 64 * j;          // kt = k*16 + t
        float a = 0.f;
        #pragma unroll
        for (int s = 0; s < 4; ++s) a += v0[s] * aw[s * 256 + kt];
        #pragma unroll
        for (int s = 0; s < 4; ++s) a += v1[s] * aw[(s + 4) * 256 + kt];
        adjs[w][kt] = a;
    }

    float y[4][16];
    #pragma unroll
    for (int pp = 0; pp < 4; ++pp)
        #pragma unroll
        for (int t = 0; t < 16; ++t) y[pp][t] = 0.f;

    // y[pp][t] += x[pp, idx[pp][n][k], lane] * adj[k][t]
    #pragma unroll
    for (int k = 0; k < KNB; ++k) {
        float xr[4];
        #pragma unroll
        for (int pp = 0; pp < 4; ++pp) {
            int row = idxs[w][pp][k];
            xr[pp] = x[(pp * NPTS + row) * FDIM + lane];   // coalesced 256B
        }
        #pragma unroll
        for (int t4 = 0; t4 < 4; ++t4) {
            f32x4 av = *(const f32x4*)&adjs[w][k * 16 + t4 * 4]; // broadcast b128
            #pragma unroll
            for (int tt = 0; tt < 4; ++tt)
                #pragma unroll
                for (int pp = 0; pp < 4; ++pp)
                    y[pp][t4 * 4 + tt] += xr[pp] * av[tt];
        }
    }

    // elu + store bf16 row p = w*4+pp, col i = t*64 + lane
    #pragma unroll
    for (int pp = 0; pp < 4; ++pp) {
        int p = w * 4 + pp;
        #pragma unroll
        for (int t = 0; t < 16; ++t) {
            float e = y[pp][t];
            e = e > 0.f ? e : __expf(e) - 1.f;
            yel[p][t * 64 + lane] = f2bf(e);
        }
    }

    __syncthreads();

    // ---- phase 2: wave w owns C-tile rows=16 points, cols c in [16w,16w+16) ----
    // out[p][c] = elu( sum_i yel[p][i] * W[c][i] + b[c] )
    const int cloc = lane & 15;
    const int kg   = lane >> 4;     // k-group 0..3, 8 k's each
    const int c    = w * 16 + cloc;
    f32x4 acc = {0.f, 0.f, 0.f, 0.f};
    #pragma unroll 8
    for (int kt = 0; kt < 32; ++kt) {
        int k0 = kt * 32 + kg * 8;
        // A fragment: lane -> (m = lane&15, k = kg*8 + j) ; same k-map used for B
        bf16x8 afrag = *(const bf16x8*)&yel[cloc][k0];
        bf16x8 bfrag;
        if (USEWB) {
            bfrag = *(const bf16x8*)&Wb[c * FAN + k0];
        } else {
            f32x4 w0 = *(const f32x4*)&W[c * FAN + k0];
            f32x4 w1 = *(const f32x4*)&W[c * FAN + k0 + 4];
            #pragma unroll
            for (int j = 0; j < 4; ++j) {
                bfrag[j]     = (short)f2bf(w0[j]);
                bfrag[j + 4] = (short)f2bf(w1[j]);
            }
        }
        acc = __builtin_amdgcn_mfma_f32_16x16x32_bf16(afrag, bfrag, acc, 0, 0, 0);
    }

    // epilogue: D row = (lane>>4)*4 + reg = local point, col = c
    float bc = bias[c];
    #pragma unroll
    for (int j = 0; j < 4; ++j) {
        int row = kg * 4 + j;
        int nn  = n0 + (row >> 2);
        int pp  = row & 3;
        float val = acc[j] + bc;
        val = val > 0.f ? val : __expf(val) - 1.f;
        if (nn == NPTS - 1) val = 0.f;   // zero_pad: last point zeroed (all b, all c)
        out[(pp * NPTS + nn) * FDIM + c] = val;
    }
}

extern "C" void kernel_launch(void* const* d_in, const int* in_sizes, int n_in,
                              void* d_out, int out_size, void* d_ws, size_t ws_size,
                              hipStream_t stream) {
    const float* x    = (const float*)d_in[0];
    const float* v    = (const float*)d_in[1];
    const float* aw   = (const float*)d_in[2];
    const float* W    = (const float*)d_in[3];
    const float* bias = (const float*)d_in[4];
    const int*   nbr  = (const int*)d_in[5];
    float* out = (float*)d_out;

    dim3 grid(NPTS / NBL), blk(256);
    if (ws_size >= (size_t)(OUTC * FAN * 2)) {
        unsigned short* Wb = (unsigned short*)d_ws;
        wconv_kernel<<<dim3(OUTC * FAN / 256), dim3(256), 0, stream>>>(W, Wb);
        paiconv_kernel<1><<<grid, blk, 0, stream>>>(x, v, aw, W, Wb, bias, nbr, out);
    } else {
        paiconv_kernel<0><<<grid, blk, 0, stream>>>(x, v, aw, W,
                                                    (const unsigned short*)nullptr,
                                                    bias, nbr, out);
    }
}